// Round 5
// baseline (86.815 us; speedup 1.0000x reference)
//
#include <hip/hip_runtime.h>
#include <math.h>

// Problem shape (fixed by harness setup_inputs): B=8, N=M=4096, D=3, fp32.
#define B_SZ 8
#define N_SZ 4096
#define M_SZ 4096
#define NQ (B_SZ * N_SZ)            // 32768 queries per direction
#define TOT (2 * NQ)                // 65536 total queries

// Cross-tile kernel: each block computes a 128x128 tile of the pairwise
// score matrix ONCE and min-reduces it along BOTH axes (the two chamfer
// directions share every dot product -> half the FLOPs of the R0-R4
// two-direction scheme). 256 threads as 16 (query groups) x 16 (target
// groups); each thread owns an 8x8 register sub-tile. Hot loop is pure
// register compute: per 2x2 micro-tile 12 fma + 4 add + 4 v_min3 =
// 5 instr per unique pair (vs 7 instr x 2 directions before).
#define BQ 128                      // pred points per block tile
#define BT 128                      // tgt points per block tile
#define NIG (N_SZ / BQ)             // 32 tiles along pred axis
#define NJG (M_SZ / BT)             // 32 tiles along tgt axis
#define NG  32                      // partials per query (rows: jg, cols: ig)

#define NBLK2 (TOT / 256)           // 256 phase-2 blocks

// ws layout (floats):
//   part[g * TOT + q] : g in [0,NG)  -> 8 MB
//     rows (pred->tgt): q = b*N + n,     written by block (b, ig=n/128, jg=g)
//     cols (tgt->pred): q = NQ + b*M + m, written by block (b, ig=g, jg=m/128)
//   bsum[NBLK2]       : at offset NG*TOT
// Every part slot is written exactly once -> no ws init, no atomics.

__device__ __forceinline__ float min3f(float a, float b, float c) {
    // fminf(fminf(a,b),c) does NOT auto-fuse to v_min3_f32 (R1); force it.
    float d;
    asm("v_min3_f32 %0, %1, %2, %3" : "=v"(d) : "v"(a), "v"(b), "v"(c));
    return d;
}

// grid: x = jg (32), y = ig (32), z = b (8) -> 8192 blocks.
__global__ __launch_bounds__(256)
void chamfer_cross_kernel(const float* __restrict__ pred,
                          const float* __restrict__ tgt,
                          float* __restrict__ part)
{
    const int b  = blockIdx.z;
    const int ig = blockIdx.y;
    const int jg = blockIdx.x;

    __shared__ float4 sq[BQ];           // pred pts: x,y,z,h  (h=|p|^2/2)
    __shared__ float4 st[BT];           // tgt  pts: x,y,z,h
    __shared__ float  redR[BQ][17];     // row partials, pad 17 -> no conflicts
    __shared__ float  redC[BT][17];     // col partials

    {
        const int k = threadIdx.x;      // 256 threads stage 128+128 points
        if (k < BQ) {
            const float* s = pred + ((size_t)b * N_SZ + ig * BQ + k) * 3;
            float x = s[0], y = s[1], z = s[2];
            sq[k] = make_float4(x, y, z, 0.5f * (x * x + y * y + z * z));
        } else {
            const int k2 = k - BQ;
            const float* s = tgt + ((size_t)b * M_SZ + jg * BT + k2) * 3;
            float x = s[0], y = s[1], z = s[2];
            st[k2] = make_float4(x, y, z, 0.5f * (x * x + y * y + z * z));
        }
    }
    __syncthreads();

    const int r = threadIdx.x >> 4;     // query group  0..15 (8 queries)
    const int c = threadIdx.x & 15;     // target group 0..15 (8 targets)

    // Own 8 queries (negated) + 8 targets in registers; one-time LDS reads.
    float qxn[8], qyn[8], qzn[8], hq[8];
    float tx[8], ty[8], tz[8], ht[8];
#pragma unroll
    for (int i = 0; i < 8; ++i) {
        float4 v = sq[r * 8 + i];
        qxn[i] = -v.x; qyn[i] = -v.y; qzn[i] = -v.z; hq[i] = v.w;
    }
#pragma unroll
    for (int j = 0; j < 8; ++j) {
        float4 v = st[c * 8 + j];
        tx[j] = v.x; ty[j] = v.y; tz[j] = v.z; ht[j] = v.w;
    }

    float mr[8], mc[8];
#pragma unroll
    for (int i = 0; i < 8; ++i) { mr[i] = 3.0e38f; mc[i] = 3.0e38f; }

    // 8x8 register tile, 2x2 micro-tiles. s = ht - q.t ; row wants
    // min_j(s) (+hq at writeout), col wants min_i(s + hq) = min d^2/2.
#pragma unroll
    for (int j = 0; j < 8; j += 2) {
#pragma unroll
        for (int i = 0; i < 8; i += 2) {
            float r00 = fmaf(qxn[i],     tx[j],     ht[j]);
            r00 = fmaf(qyn[i],     ty[j],     r00);
            r00 = fmaf(qzn[i],     tz[j],     r00);
            float r01 = fmaf(qxn[i],     tx[j + 1], ht[j + 1]);
            r01 = fmaf(qyn[i],     ty[j + 1], r01);
            r01 = fmaf(qzn[i],     tz[j + 1], r01);
            float r10 = fmaf(qxn[i + 1], tx[j],     ht[j]);
            r10 = fmaf(qyn[i + 1], ty[j],     r10);
            r10 = fmaf(qzn[i + 1], tz[j],     r10);
            float r11 = fmaf(qxn[i + 1], tx[j + 1], ht[j + 1]);
            r11 = fmaf(qyn[i + 1], ty[j + 1], r11);
            r11 = fmaf(qzn[i + 1], tz[j + 1], r11);
            mr[i]     = min3f(mr[i],     r00, r01);
            mr[i + 1] = min3f(mr[i + 1], r10, r11);
            float c00 = r00 + hq[i];
            float c10 = r10 + hq[i + 1];
            mc[j]     = min3f(mc[j],     c00, c10);
            float c01 = r01 + hq[i];
            float c11 = r11 + hq[i + 1];
            mc[j + 1] = min3f(mc[j + 1], c01, c11);
        }
    }

    // Cross-thread reduction: 16 partials per row / per col.
#pragma unroll
    for (int i = 0; i < 8; ++i) redR[r * 8 + i][c] = mr[i] + hq[i];
#pragma unroll
    for (int j = 0; j < 8; ++j) redC[c * 8 + j][r] = mc[j];
    __syncthreads();

    const int tid = threadIdx.x;
    if (tid < BQ) {                     // 128 threads finish the 128 rows
        float m = 3.0e38f;
#pragma unroll
        for (int k = 0; k < 16; ++k) m = fminf(m, redR[tid][k]);
        part[(size_t)jg * TOT + (size_t)b * N_SZ + ig * BQ + tid] = m;
    } else {                            // 128 threads finish the 128 cols
        const int t = tid - BQ;
        float m = 3.0e38f;
#pragma unroll
        for (int k = 0; k < 16; ++k) m = fminf(m, redC[t][k]);
        part[(size_t)ig * TOT + NQ + (size_t)b * M_SZ + jg * BT + t] = m;
    }
}

// Phase 2: one query per thread; 32 coalesced independent loads; block sum.
__global__ __launch_bounds__(256)
void chamfer_combine_kernel(const float* __restrict__ part,
                            float* __restrict__ bsum)
{
    const int q = blockIdx.x * 256 + threadIdx.x;
    float m = 3.0e38f;
#pragma unroll
    for (int g = 0; g < NG; ++g) m = fminf(m, part[(size_t)g * TOT + q]);
    float d = sqrtf(2.0f * fmaxf(m, 0.0f));
#pragma unroll
    for (int off = 32; off > 0; off >>= 1) d += __shfl_down(d, off);
    __shared__ float rs[4];
    if ((threadIdx.x & 63) == 0) rs[threadIdx.x >> 6] = d;
    __syncthreads();
    if (threadIdx.x == 0) bsum[blockIdx.x] = rs[0] + rs[1] + rs[2] + rs[3];
}

// Phase 3: one wave sums the 256 block partials.
__global__ __launch_bounds__(64)
void chamfer_final_kernel(const float* __restrict__ bsum,
                          float* __restrict__ out)
{
    float s = 0.0f;
#pragma unroll
    for (int i = 0; i < NBLK2 / 64; ++i) s += bsum[threadIdx.x + i * 64];
#pragma unroll
    for (int off = 32; off > 0; off >>= 1) s += __shfl_down(s, off);
    // loss = mean(min_p2t) + mean(min_t2p) = (sum of all NN dists)/NQ (N==M)
    if (threadIdx.x == 0) out[0] = s * (1.0f / (float)NQ);
}

extern "C" void kernel_launch(void* const* d_in, const int* in_sizes, int n_in,
                              void* d_out, int out_size, void* d_ws, size_t ws_size,
                              hipStream_t stream) {
    const float* pred = (const float*)d_in[0];  // [B,N,3]
    const float* tgt  = (const float*)d_in[1];  // [B,M,3]
    float* out = (float*)d_out;

    float* part = (float*)d_ws;                 // NG*TOT floats = 8 MB
    float* bsum = part + (size_t)NG * TOT;      // NBLK2 floats

    dim3 grid1(NJG, NIG, B_SZ);                 // (32, 32, 8) = 8192 blocks
    chamfer_cross_kernel<<<grid1, 256, 0, stream>>>(pred, tgt, part);
    chamfer_combine_kernel<<<NBLK2, 256, 0, stream>>>(part, bsum);
    chamfer_final_kernel<<<1, 64, 0, stream>>>(bsum, out);
}

// Round 6
// 84.129 us; speedup vs baseline: 1.0319x; 1.0319x over previous
//
#include <hip/hip_runtime.h>
#include <math.h>

// Problem shape (fixed by harness setup_inputs): B=8, N=M=4096, D=3, fp32.
#define B_SZ 8
#define N_SZ 4096
#define M_SZ 4096
#define NQ (B_SZ * N_SZ)            // 32768 queries per direction
#define TOT (2 * NQ)                // 65536 total queries

// Symmetric cross-tile kernel, FAT blocks. Each block computes a 256x256
// tile of the pairwise score matrix ONCE and min-reduces it along BOTH
// axes (the two chamfer directions share every dot product). 256 threads
// as 16x16 groups; each thread owns a 16x16 register micro-tile = 256
// unique pairs, 1280 pure-register VALU insts between barriers.
// R5 lesson: 128x128 tiles (64 pairs/thread) drown in per-block overhead;
// 256x256 amortizes staging/reduction 4x while keeping the half-FLOPs win.
#define BQ 256                      // pred points per block tile
#define BT 256                      // tgt points per block tile
#define NIG (N_SZ / BQ)             // 16 tiles along pred axis
#define NJG (M_SZ / BT)             // 16 tiles along tgt axis
#define NG  16                      // partials per query

#define NBLK2 (TOT / 256)           // 256 phase-2 blocks

// ws layout (floats):
//   part[g * TOT + q] : g in [0,NG)  -> 4 MB
//     rows (pred->tgt): q = b*N + n,      written by block (b, ig=n/256, jg=g)
//     cols (tgt->pred): q = NQ + b*M + m, written by block (b, ig=g, jg=m/256)
//   bsum[NBLK2]       : at offset NG*TOT
// Every part slot is written exactly once -> no ws init, no atomics.

__device__ __forceinline__ float min3f(float a, float b, float c) {
    // fminf(fminf(a,b),c) does NOT auto-fuse to v_min3_f32 (R1); force it.
    float d;
    asm("v_min3_f32 %0, %1, %2, %3" : "=v"(d) : "v"(a), "v"(b), "v"(c));
    return d;
}

// grid: x = jg (16), y = ig (16), z = b (8) -> 2048 blocks (8 per CU).
__global__ __launch_bounds__(256)
void chamfer_cross_kernel(const float* __restrict__ pred,
                          const float* __restrict__ tgt,
                          float* __restrict__ part)
{
    const int b  = blockIdx.z;
    const int ig = blockIdx.y;
    const int jg = blockIdx.x;
    const int tid = threadIdx.x;

    __shared__ float4 sq[BQ];           // pred pts: x,y,z,h  (h=|p|^2/2)
    __shared__ float4 st[BT];           // tgt  pts: x,y,z,h
    __shared__ float  red[256][17];     // reduction scratch (stride 17:
                                        // bank-conflict-free both phases)

    {   // 256 threads stage 256+256 points (coalesced 12B/thread runs).
        const float* sp = pred + ((size_t)b * N_SZ + ig * BQ + tid) * 3;
        float x = sp[0], y = sp[1], z = sp[2];
        sq[tid] = make_float4(x, y, z, 0.5f * (x * x + y * y + z * z));
        const float* sv = tgt + ((size_t)b * M_SZ + jg * BT + tid) * 3;
        x = sv[0]; y = sv[1]; z = sv[2];
        st[tid] = make_float4(x, y, z, 0.5f * (x * x + y * y + z * z));
    }
    __syncthreads();

    const int r = tid >> 4;             // query group  0..15 (16 queries)
    const int c = tid & 15;             // target group 0..15 (16 targets)

    // Own 16 queries (negated) + 16 targets in registers (one-time LDS reads,
    // all indices compile-time -> stays in VGPRs).
    float qxn[16], qyn[16], qzn[16], hq[16];
    float tx[16], ty[16], tz[16], ht[16];
#pragma unroll
    for (int i = 0; i < 16; ++i) {
        float4 v = sq[r * 16 + i];
        qxn[i] = -v.x; qyn[i] = -v.y; qzn[i] = -v.z; hq[i] = v.w;
    }
#pragma unroll
    for (int j = 0; j < 16; ++j) {
        float4 v = st[c * 16 + j];
        tx[j] = v.x; ty[j] = v.y; tz[j] = v.z; ht[j] = v.w;
    }

    float mr[16], mc[16];
#pragma unroll
    for (int i = 0; i < 16; ++i) { mr[i] = 3.0e38f; mc[i] = 3.0e38f; }

    // 16x16 register tile in 2x2 micro-tiles: 12 fma + 4 add + 4 min3 per
    // 4 unique pairs = 5 insts/pair (vs 7 insts/pair PER DIRECTION before).
    // s = ht - q.t ; rows take min_j(s) (+hq at writeout), cols min_i(s+hq).
#pragma unroll
    for (int j = 0; j < 16; j += 2) {
#pragma unroll
        for (int i = 0; i < 16; i += 2) {
            float r00 = fmaf(qxn[i],     tx[j],     ht[j]);
            r00 = fmaf(qyn[i],     ty[j],     r00);
            r00 = fmaf(qzn[i],     tz[j],     r00);
            float r01 = fmaf(qxn[i],     tx[j + 1], ht[j + 1]);
            r01 = fmaf(qyn[i],     ty[j + 1], r01);
            r01 = fmaf(qzn[i],     tz[j + 1], r01);
            float r10 = fmaf(qxn[i + 1], tx[j],     ht[j]);
            r10 = fmaf(qyn[i + 1], ty[j],     r10);
            r10 = fmaf(qzn[i + 1], tz[j],     r10);
            float r11 = fmaf(qxn[i + 1], tx[j + 1], ht[j + 1]);
            r11 = fmaf(qyn[i + 1], ty[j + 1], r11);
            r11 = fmaf(qzn[i + 1], tz[j + 1], r11);
            mr[i]     = min3f(mr[i],     r00, r01);
            mr[i + 1] = min3f(mr[i + 1], r10, r11);
            float c00 = r00 + hq[i];
            float c10 = r10 + hq[i + 1];
            mc[j]     = min3f(mc[j],     c00, c10);
            float c01 = r01 + hq[i];
            float c11 = r11 + hq[i + 1];
            mc[j + 1] = min3f(mc[j + 1], c01, c11);
        }
    }

    // Row reduction: 16 partials per row across the c-groups.
#pragma unroll
    for (int i = 0; i < 16; ++i) red[r * 16 + i][c] = mr[i] + hq[i];
    __syncthreads();
    {
        float m = 3.0e38f;
#pragma unroll
        for (int k = 0; k < 16; k += 2) m = min3f(m, red[tid][k], red[tid][k + 1]);
        part[(size_t)jg * TOT + (size_t)b * N_SZ + ig * BQ + tid] = m;
    }
    __syncthreads();

    // Col reduction (reuse the same scratch).
#pragma unroll
    for (int j = 0; j < 16; ++j) red[c * 16 + j][r] = mc[j];
    __syncthreads();
    {
        float m = 3.0e38f;
#pragma unroll
        for (int k = 0; k < 16; k += 2) m = min3f(m, red[tid][k], red[tid][k + 1]);
        part[(size_t)ig * TOT + NQ + (size_t)b * M_SZ + jg * BT + tid] = m;
    }
}

// Phase 2: one query per thread; 16 coalesced independent loads; block sum.
__global__ __launch_bounds__(256)
void chamfer_combine_kernel(const float* __restrict__ part,
                            float* __restrict__ bsum)
{
    const int q = blockIdx.x * 256 + threadIdx.x;
    float m = 3.0e38f;
#pragma unroll
    for (int g = 0; g < NG; ++g) m = fminf(m, part[(size_t)g * TOT + q]);
    float d = sqrtf(2.0f * fmaxf(m, 0.0f));
#pragma unroll
    for (int off = 32; off > 0; off >>= 1) d += __shfl_down(d, off);
    __shared__ float rs[4];
    if ((threadIdx.x & 63) == 0) rs[threadIdx.x >> 6] = d;
    __syncthreads();
    if (threadIdx.x == 0) bsum[blockIdx.x] = rs[0] + rs[1] + rs[2] + rs[3];
}

// Phase 3: one wave sums the 256 block partials.
__global__ __launch_bounds__(64)
void chamfer_final_kernel(const float* __restrict__ bsum,
                          float* __restrict__ out)
{
    float s = 0.0f;
#pragma unroll
    for (int i = 0; i < NBLK2 / 64; ++i) s += bsum[threadIdx.x + i * 64];
#pragma unroll
    for (int off = 32; off > 0; off >>= 1) s += __shfl_down(s, off);
    // loss = mean(min_p2t) + mean(min_t2p) = (sum of all NN dists)/NQ (N==M)
    if (threadIdx.x == 0) out[0] = s * (1.0f / (float)NQ);
}

extern "C" void kernel_launch(void* const* d_in, const int* in_sizes, int n_in,
                              void* d_out, int out_size, void* d_ws, size_t ws_size,
                              hipStream_t stream) {
    const float* pred = (const float*)d_in[0];  // [B,N,3]
    const float* tgt  = (const float*)d_in[1];  // [B,M,3]
    float* out = (float*)d_out;

    float* part = (float*)d_ws;                 // NG*TOT floats = 4 MB
    float* bsum = part + (size_t)NG * TOT;      // NBLK2 floats

    dim3 grid1(NJG, NIG, B_SZ);                 // (16, 16, 8) = 2048 blocks
    chamfer_cross_kernel<<<grid1, 256, 0, stream>>>(pred, tgt, part);
    chamfer_combine_kernel<<<NBLK2, 256, 0, stream>>>(part, bsum);
    chamfer_final_kernel<<<1, 64, 0, stream>>>(bsum, out);
}